// Round 3
// baseline (475.675 us; speedup 1.0000x reference)
//
#include <hip/hip_runtime.h>
#include <math.h>

#define N_NODES 100000
#define N_EDGES 1600000
#define D_IN 256
#define D_OUT 128

// ---- workspace layout (bytes) ------------------------------------------
#define OFF_SUPPORT 0
#define OFF_COUNTS  51200000
#define OFF_CSREV   51600008
#define OFF_BSUMS   64400008
#define OFF_WTHI    64400416
#define OFF_WTLO    64465952

#define SCAN_CHUNK  1024
#define SCAN_BLOCKS ((N_NODES + SCAN_CHUNK - 1) / SCAN_CHUNK)  // 98

#define GB 128                                   // node rows per GEMM tile
#define GEMM_BLOCKS ((N_NODES + GB - 1) / GB)    // 782
#define EDGE_BLOCKS ((N_EDGES + 255) / 256)      // 6250

typedef __attribute__((ext_vector_type(8))) short s8v;   // 8 bf16 = 4 VGPR
typedef __attribute__((ext_vector_type(4))) float f4v;   // mfma acc

__device__ __forceinline__ short f2bf(float x) {   // RNE fp32 -> bf16 bits
  unsigned u = __float_as_uint(x);
  unsigned r = u + 0x7FFF + ((u >> 16) & 1);
  return (short)(r >> 16);
}
__device__ __forceinline__ float bf2f(short h) {
  return __uint_as_float(((unsigned)(unsigned short)h) << 16);
}

// split 8 fp32 into bf16 hi/lo fragments (in-register)
__device__ __forceinline__ void cvt8(float4 a, float4 b, s8v& h, s8v& l) {
  float f[8] = {a.x, a.y, a.z, a.w, b.x, b.y, b.z, b.w};
#pragma unroll
  for (int i = 0; i < 8; i++) {
    short hh = f2bf(f[i]);
    h[i] = hh;
    l[i] = f2bf(f[i] - bf2f(hh));
  }
}

typedef const float __attribute__((address_space(1)))* gas1f;
typedef float __attribute__((address_space(3)))* las3f;
__device__ __forceinline__ void gload_lds16(const float* g, float* l) {
  __builtin_amdgcn_global_load_lds((gas1f)g, (las3f)l, 16, 0, 0);
}

// ---------------------------------------------------------------------------
// K0: W[k][n] fp32 -> wt_hi/wt_lo[n][k] bf16 split (once; 32K elems)
// ---------------------------------------------------------------------------
__global__ __launch_bounds__(256) void wconv_kernel(
    const float* __restrict__ W, short* __restrict__ wt_hi,
    short* __restrict__ wt_lo) {
  int idx = blockIdx.x * 256 + threadIdx.x;
  int k = idx >> 7;
  int n = idx & 127;
  float v = W[idx];
  short h = f2bf(v);
  wt_hi[n * 256 + k] = h;
  wt_lo[n * 256 + k] = f2bf(v - bf2f(h));
}

// ---------------------------------------------------------------------------
// Little's-law GEMM: support = X*W + b, barrier-free, 2-deep DMA pipeline.
// Per k-step VMEM issue order (pinned by sched_barrier):
//   ds_read frags(t) ; lgkmcnt(0) ; B loads (16) ; stage A(t+2) DMA (4)
// In-order vmcnt retirement => compiler's own wait for the B registers is
// vmcnt(4): the A(t+2) DMA stays in flight across the whole MFMA phase.
// No vmcnt(0) anywhere in the loop. Manual waits: only the loop-top
// vmcnt(4) (compiler can't see DMA->LDS feeding the ds_reads).
// Per wave ~4-16 KB outstanding; ~8 waves/CU -> >50 KB/CU in flight.
// Fragment math identical to the verified round-0 kernel -> same absmax.
// ---------------------------------------------------------------------------
__global__ __launch_bounds__(256, 2) void gemm_kernel(
    const float* __restrict__ input, const short* __restrict__ wt_hi,
    const short* __restrict__ wt_lo, const float* __restrict__ b,
    float* __restrict__ support) {
  __shared__ float Af[4][2][32][32];   // 32 KB: wave x dbuf x row x k
  const int gb = blockIdx.x;
  const int t = threadIdx.x;
  const int lane = t & 63;
  const int wv = t >> 6;
  const int qm = lane & 15;
  const int quad = lane >> 4;
  const int node0 = gb * GB;

  const int srow = lane >> 3;          // 0..7
  const int gc = (lane & 7) ^ srow;    // swizzled 16B-chunk in source row

  auto stage = [&](int kt, int buf) {
#pragma unroll
    for (int j = 0; j < 4; ++j) {
      int nd = node0 + wv * 32 + j * 8 + srow;
      if (nd > N_NODES - 1) nd = N_NODES - 1;   // clamp; garbage never stored
      gload_lds16(input + (size_t)nd * D_IN + kt * 32 + gc * 4,
                  &Af[wv][buf][j * 8][0]);
    }
  };

  stage(0, 0);
  stage(1, 1);

  f4v acc[2][8];
#pragma unroll
  for (int mt = 0; mt < 2; mt++)
#pragma unroll
    for (int nt = 0; nt < 8; nt++) acc[mt][nt] = (f4v){0.f, 0.f, 0.f, 0.f};

  const int p0 = (2 * quad) ^ (qm & 7);      // physical chunk of logical 2q
  const int p1 = (2 * quad + 1) ^ (qm & 7);  // physical chunk of logical 2q+1

#pragma unroll
  for (int kt = 0; kt < 8; ++kt) {
    const int cb = kt & 1;
    // A(kt) staged?  queue(top, steady): [A(t+1)] = 4; iter0: [A0,A1] = 8.
    asm volatile("s_waitcnt vmcnt(4)" ::: "memory");
    float4 x00 = *(const float4*)&Af[wv][cb][qm][p0 * 4];
    float4 x01 = *(const float4*)&Af[wv][cb][qm][p1 * 4];
    float4 x10 = *(const float4*)&Af[wv][cb][qm + 16][p0 * 4];
    float4 x11 = *(const float4*)&Af[wv][cb][qm + 16][p1 * 4];
    // frag reads retired before this buffer is re-staged below
    asm volatile("s_waitcnt lgkmcnt(0)" ::: "memory");
    __builtin_amdgcn_sched_barrier(0);

    const int koff = kt * 32 + quad * 8;
    s8v bh[8], bl[8];
#pragma unroll
    for (int nt = 0; nt < 8; ++nt) {
      size_t bo = (size_t)(nt * 16 + qm) * 256 + koff;
      bh[nt] = *(const s8v*)(wt_hi + bo);
      bl[nt] = *(const s8v*)(wt_lo + bo);
    }
    __builtin_amdgcn_sched_barrier(0);
    if (kt < 6) stage(kt + 2, cb);       // newest in queue -> survives B-waits
    __builtin_amdgcn_sched_barrier(0);

    s8v ah0, al0, ah1, al1;
    cvt8(x00, x01, ah0, al0);
    cvt8(x10, x11, ah1, al1);
#pragma unroll
    for (int nt = 0; nt < 8; ++nt) {
      acc[0][nt] = __builtin_amdgcn_mfma_f32_16x16x32_bf16(ah0, bh[nt], acc[0][nt], 0, 0, 0);
      acc[0][nt] = __builtin_amdgcn_mfma_f32_16x16x32_bf16(ah0, bl[nt], acc[0][nt], 0, 0, 0);
      acc[0][nt] = __builtin_amdgcn_mfma_f32_16x16x32_bf16(al0, bh[nt], acc[0][nt], 0, 0, 0);
      acc[1][nt] = __builtin_amdgcn_mfma_f32_16x16x32_bf16(ah1, bh[nt], acc[1][nt], 0, 0, 0);
      acc[1][nt] = __builtin_amdgcn_mfma_f32_16x16x32_bf16(ah1, bl[nt], acc[1][nt], 0, 0, 0);
      acc[1][nt] = __builtin_amdgcn_mfma_f32_16x16x32_bf16(al1, bh[nt], acc[1][nt], 0, 0, 0);
    }
  }

  float bias[8];
#pragma unroll
  for (int nt = 0; nt < 8; nt++) bias[nt] = b[nt * 16 + qm];
#pragma unroll
  for (int mt = 0; mt < 2; mt++) {
#pragma unroll
    for (int nt = 0; nt < 8; nt++) {
      int col = nt * 16 + qm;
#pragma unroll
      for (int r = 0; r < 4; r++) {
        int node = node0 + wv * 32 + mt * 16 + quad * 4 + r;
        if (node < N_NODES)
          support[(size_t)node * D_OUT + col] = acc[mt][nt][r] + bias[nt];
      }
    }
  }
}

// K1b: edge histogram (separate dispatch for clean per-kernel counters)
__global__ __launch_bounds__(256) void hist_kernel(
    const int* __restrict__ erow, int* __restrict__ counts,
    int* __restrict__ pos_e) {
  int e = blockIdx.x * 256 + threadIdx.x;
  if (e < N_EDGES) pos_e[e] = atomicAdd(&counts[erow[e]], 1);
}

// K2: atomic-free CSR bucket scatter
__global__ __launch_bounds__(256) void build_kernel(
    const int* __restrict__ erow, const int* __restrict__ ecol,
    const float* __restrict__ eval, const int* __restrict__ offsets,
    const int* __restrict__ pos_e, int2* __restrict__ csr_ev) {
  int e = blockIdx.x * 256 + threadIdx.x;
  if (e < N_EDGES) {
    int idx = offsets[erow[e]] + pos_e[e];
    csr_ev[idx] = make_int2(ecol[e], __float_as_int(eval[e]));
  }
}

// ---------------------------------------------------------------------------
// 3-phase exclusive scan over counts (verified)
// ---------------------------------------------------------------------------
__global__ __launch_bounds__(256) void scan_phase1(const int* __restrict__ counts,
                                                   int* __restrict__ bsums) {
  __shared__ int ts[256];
  int t = threadIdx.x;
  int idx0 = blockIdx.x * SCAN_CHUNK + t * 4;
  int s = 0;
#pragma unroll
  for (int i = 0; i < 4; i++)
    if (idx0 + i < N_NODES) s += counts[idx0 + i];
  ts[t] = s;
  __syncthreads();
#pragma unroll
  for (int off = 128; off > 0; off >>= 1) {
    if (t < off) ts[t] += ts[t + off];
    __syncthreads();
  }
  if (t == 0) bsums[blockIdx.x] = ts[0];
}

__global__ __launch_bounds__(128) void scan_phase2(int* __restrict__ bsums) {
  __shared__ int s[128];
  int t = threadIdx.x;
  int v = (t < SCAN_BLOCKS) ? bsums[t] : 0;
  s[t] = v;
  __syncthreads();
#pragma unroll
  for (int off = 1; off < 128; off <<= 1) {
    int x = (t >= off) ? s[t - off] : 0;
    __syncthreads();
    s[t] += x;
    __syncthreads();
  }
  if (t < SCAN_BLOCKS) bsums[t] = s[t] - v;  // exclusive
}

__global__ __launch_bounds__(256) void scan_phase3(int* __restrict__ counts,
                                                   const int* __restrict__ bsums) {
  __shared__ int ts[256];
  int t = threadIdx.x;
  int b = blockIdx.x;
  int idx0 = b * SCAN_CHUNK + t * 4;
  int v[4];
  int s = 0;
#pragma unroll
  for (int i = 0; i < 4; i++) {
    v[i] = (idx0 + i < N_NODES) ? counts[idx0 + i] : 0;
    s += v[i];
  }
  ts[t] = s;
  __syncthreads();
#pragma unroll
  for (int off = 1; off < 256; off <<= 1) {
    int x = (t >= off) ? ts[t - off] : 0;
    __syncthreads();
    ts[t] += x;
    __syncthreads();
  }
  int run = bsums[b] + ts[t] - s;
#pragma unroll
  for (int i = 0; i < 4; i++) {
    int idx = idx0 + i;
    if (idx < N_NODES) counts[idx] = run;
    run += v[i];
  }
  if (b == 0 && t == 0) counts[N_NODES] = N_EDGES;
}

// ---------------------------------------------------------------------------
// Gather-aggregate + fused tanh.  32 lanes x float4 per row.
// ---------------------------------------------------------------------------
__global__ __launch_bounds__(256) void agg_kernel(
    const int* __restrict__ offsets, const int2* __restrict__ csr_ev,
    const float* __restrict__ support, float* __restrict__ out) {
  int r = blockIdx.x * 8 + (threadIdx.x >> 5);
  int l4 = (threadIdx.x & 31) * 4;          // feature quad
  int beg = offsets[r];
  int end = offsets[r + 1];
  float4 acc = make_float4(0.f, 0.f, 0.f, 0.f);
  int j = beg;
  for (; j + 8 <= end; j += 8) {
    int2 e[8];
    float4 s[8];
#pragma unroll
    for (int u = 0; u < 8; u++) e[u] = csr_ev[j + u];
#pragma unroll
    for (int u = 0; u < 8; u++)
      s[u] = *(const float4*)(support + (size_t)e[u].x * D_OUT + l4);
#pragma unroll
    for (int u = 0; u < 8; u++) {
      float v = __int_as_float(e[u].y);
      acc.x = fmaf(v, s[u].x, acc.x);
      acc.y = fmaf(v, s[u].y, acc.y);
      acc.z = fmaf(v, s[u].z, acc.z);
      acc.w = fmaf(v, s[u].w, acc.w);
    }
  }
  for (; j < end; j++) {
    int2 ev = csr_ev[j];
    float4 s = *(const float4*)(support + (size_t)ev.x * D_OUT + l4);
    float v = __int_as_float(ev.y);
    acc.x = fmaf(v, s.x, acc.x);
    acc.y = fmaf(v, s.y, acc.y);
    acc.z = fmaf(v, s.z, acc.z);
    acc.w = fmaf(v, s.w, acc.w);
  }
  *(float4*)(out + (size_t)r * D_OUT + l4) =
      make_float4(tanhf(acc.x), tanhf(acc.y), tanhf(acc.z), tanhf(acc.w));
}

extern "C" void kernel_launch(void* const* d_in, const int* in_sizes, int n_in,
                              void* d_out, int out_size, void* d_ws, size_t ws_size,
                              hipStream_t stream) {
  const float* input = (const float*)d_in[0];
  const int* erow = (const int*)d_in[1];
  const int* ecol = (const int*)d_in[2];
  const float* eval = (const float*)d_in[3];
  const float* W = (const float*)d_in[4];
  const float* b = (const float*)d_in[5];
  float* out = (float*)d_out;

  char* ws = (char*)d_ws;
  float* support = (float*)(ws + OFF_SUPPORT);
  int* counts = (int*)(ws + OFF_COUNTS);  // becomes offsets after scan
  int2* csr_ev = (int2*)(ws + OFF_CSREV);
  int* bsums = (int*)(ws + OFF_BSUMS);
  short* wt_hi = (short*)(ws + OFF_WTHI);
  short* wt_lo = (short*)(ws + OFF_WTLO);
  int* pos_e = (int*)d_out;  // d_out as scratch; agg overwrites it last

  // K0: convert W once (transposed bf16 hi/lo)
  hipLaunchKernelGGL(wconv_kernel, dim3((D_IN * D_OUT) / 256), dim3(256), 0,
                     stream, W, wt_hi, wt_lo);
  hipMemsetAsync(ws + OFF_COUNTS, 0, (size_t)(N_NODES + 1) * 4, stream);

  // histogram and GEMM as separate dispatches (per-kernel counters)
  hipLaunchKernelGGL(hist_kernel, dim3(EDGE_BLOCKS), dim3(256), 0, stream,
                     erow, counts, pos_e);
  hipLaunchKernelGGL(gemm_kernel, dim3(GEMM_BLOCKS), dim3(256), 0, stream,
                     input, wt_hi, wt_lo, b, support);
  // exclusive scan: counts -> offsets
  hipLaunchKernelGGL(scan_phase1, dim3(SCAN_BLOCKS), dim3(256), 0, stream,
                     counts, bsums);
  hipLaunchKernelGGL(scan_phase2, dim3(1), dim3(128), 0, stream, bsums);
  hipLaunchKernelGGL(scan_phase3, dim3(SCAN_BLOCKS), dim3(256), 0, stream,
                     counts, bsums);
  // K2: atomic-free CSR bucket scatter
  hipLaunchKernelGGL(build_kernel, dim3(EDGE_BLOCKS), dim3(256), 0, stream,
                     erow, ecol, eval, counts, pos_e, csr_ev);
  // out = tanh(A_csr * support)
  hipLaunchKernelGGL(agg_kernel, dim3(N_NODES / 8), dim3(256), 0, stream,
                     counts, csr_ev, support, out);
}

// Round 4
// 438.190 us; speedup vs baseline: 1.0855x; 1.0855x over previous
//
#include <hip/hip_runtime.h>
#include <math.h>

#define N_NODES 100000
#define N_EDGES 1600000
#define D_IN 256
#define D_OUT 128

// ---- workspace layout (bytes) ------------------------------------------
#define OFF_SUPPORT 0
#define OFF_COUNTS  51200000
#define OFF_CSREV   51600008
#define OFF_BSUMS   64400008
#define OFF_WTHI    64400416
#define OFF_WTLO    64465952

#define SCAN_CHUNK  1024
#define SCAN_BLOCKS ((N_NODES + SCAN_CHUNK - 1) / SCAN_CHUNK)  // 98

#define GB 128                                   // node rows per GEMM tile
#define GEMM_BLOCKS ((N_NODES + GB - 1) / GB)    // 782
#define EDGE_BLOCKS ((N_EDGES + 255) / 256)      // 6250

typedef __attribute__((ext_vector_type(8))) short s8v;   // 8 bf16 = 4 VGPR
typedef __attribute__((ext_vector_type(4))) float f4v;   // mfma acc

__device__ __forceinline__ short f2bf(float x) {   // RNE fp32 -> bf16 bits
  unsigned u = __float_as_uint(x);
  unsigned r = u + 0x7FFF + ((u >> 16) & 1);
  return (short)(r >> 16);
}
__device__ __forceinline__ float bf2f(short h) {
  return __uint_as_float(((unsigned)(unsigned short)h) << 16);
}

// split 8 fp32 into bf16 hi/lo fragments (in-register)
__device__ __forceinline__ void cvt8(float4 a, float4 b, s8v& h, s8v& l) {
  float f[8] = {a.x, a.y, a.z, a.w, b.x, b.y, b.z, b.w};
#pragma unroll
  for (int i = 0; i < 8; i++) {
    short hh = f2bf(f[i]);
    h[i] = hh;
    l[i] = f2bf(f[i] - bf2f(hh));
  }
}

typedef const float __attribute__((address_space(1)))* gas1f;
typedef float __attribute__((address_space(3)))* las3f;
__device__ __forceinline__ void gload_lds16(const float* g, float* l) {
  __builtin_amdgcn_global_load_lds((gas1f)g, (las3f)l, 16, 0, 0);
}

// ---------------------------------------------------------------------------
// K0: W[k][n] fp32 -> wt_hi/wt_lo[n][k] bf16 split (once; 32K elems)
//     + zero the counts array (replaces a separate memset dispatch)
// ---------------------------------------------------------------------------
__global__ __launch_bounds__(256) void wconv_kernel(
    const float* __restrict__ W, short* __restrict__ wt_hi,
    short* __restrict__ wt_lo, int* __restrict__ counts) {
  int idx = blockIdx.x * 256 + threadIdx.x;   // grid 128 -> 32768
  int k = idx >> 7;
  int n = idx & 127;
  float v = W[idx];
  short h = f2bf(v);
  wt_hi[n * 256 + k] = h;
  wt_lo[n * 256 + k] = f2bf(v - bf2f(h));
  for (int i = idx; i < N_NODES + 1; i += 32768) counts[i] = 0;
}

// ---------------------------------------------------------------------------
// Little's-law GEMM body (verified round 3): barrier-free, 2-deep DMA
// pipeline, per-wave-private LDS slices, XOR-swizzled staging.
// ---------------------------------------------------------------------------
__device__ __forceinline__ void gemm_body(
    int gb, const float* __restrict__ input, const short* __restrict__ wt_hi,
    const short* __restrict__ wt_lo, const float* __restrict__ b,
    float* __restrict__ support) {
  __shared__ float Af[4][2][32][32];   // 32 KB: wave x dbuf x row x k
  const int t = threadIdx.x;
  const int lane = t & 63;
  const int wv = t >> 6;
  const int qm = lane & 15;
  const int quad = lane >> 4;
  const int node0 = gb * GB;

  const int srow = lane >> 3;          // 0..7
  const int gc = (lane & 7) ^ srow;    // swizzled 16B-chunk in source row

  auto stage = [&](int kt, int buf) {
#pragma unroll
    for (int j = 0; j < 4; ++j) {
      int nd = node0 + wv * 32 + j * 8 + srow;
      if (nd > N_NODES - 1) nd = N_NODES - 1;   // clamp; garbage never stored
      gload_lds16(input + (size_t)nd * D_IN + kt * 32 + gc * 4,
                  &Af[wv][buf][j * 8][0]);
    }
  };

  stage(0, 0);
  stage(1, 1);

  f4v acc[2][8];
#pragma unroll
  for (int mt = 0; mt < 2; mt++)
#pragma unroll
    for (int nt = 0; nt < 8; nt++) acc[mt][nt] = (f4v){0.f, 0.f, 0.f, 0.f};

  const int p0 = (2 * quad) ^ (qm & 7);      // physical chunk of logical 2q
  const int p1 = (2 * quad + 1) ^ (qm & 7);  // physical chunk of logical 2q+1

#pragma unroll
  for (int kt = 0; kt < 8; ++kt) {
    const int cb = kt & 1;
    asm volatile("s_waitcnt vmcnt(4)" ::: "memory");
    float4 x00 = *(const float4*)&Af[wv][cb][qm][p0 * 4];
    float4 x01 = *(const float4*)&Af[wv][cb][qm][p1 * 4];
    float4 x10 = *(const float4*)&Af[wv][cb][qm + 16][p0 * 4];
    float4 x11 = *(const float4*)&Af[wv][cb][qm + 16][p1 * 4];
    asm volatile("s_waitcnt lgkmcnt(0)" ::: "memory");
    __builtin_amdgcn_sched_barrier(0);

    const int koff = kt * 32 + quad * 8;
    s8v bh[8], bl[8];
#pragma unroll
    for (int nt = 0; nt < 8; ++nt) {
      size_t bo = (size_t)(nt * 16 + qm) * 256 + koff;
      bh[nt] = *(const s8v*)(wt_hi + bo);
      bl[nt] = *(const s8v*)(wt_lo + bo);
    }
    __builtin_amdgcn_sched_barrier(0);
    if (kt < 6) stage(kt + 2, cb);       // newest in queue -> survives B-waits
    __builtin_amdgcn_sched_barrier(0);

    s8v ah0, al0, ah1, al1;
    cvt8(x00, x01, ah0, al0);
    cvt8(x10, x11, ah1, al1);
#pragma unroll
    for (int nt = 0; nt < 8; ++nt) {
      acc[0][nt] = __builtin_amdgcn_mfma_f32_16x16x32_bf16(ah0, bh[nt], acc[0][nt], 0, 0, 0);
      acc[0][nt] = __builtin_amdgcn_mfma_f32_16x16x32_bf16(ah0, bl[nt], acc[0][nt], 0, 0, 0);
      acc[0][nt] = __builtin_amdgcn_mfma_f32_16x16x32_bf16(al0, bh[nt], acc[0][nt], 0, 0, 0);
      acc[1][nt] = __builtin_amdgcn_mfma_f32_16x16x32_bf16(ah1, bh[nt], acc[1][nt], 0, 0, 0);
      acc[1][nt] = __builtin_amdgcn_mfma_f32_16x16x32_bf16(ah1, bl[nt], acc[1][nt], 0, 0, 0);
      acc[1][nt] = __builtin_amdgcn_mfma_f32_16x16x32_bf16(al1, bh[nt], acc[1][nt], 0, 0, 0);
    }
  }

  float bias[8];
#pragma unroll
  for (int nt = 0; nt < 8; nt++) bias[nt] = b[nt * 16 + qm];
#pragma unroll
  for (int mt = 0; mt < 2; mt++) {
#pragma unroll
    for (int nt = 0; nt < 8; nt++) {
      int col = nt * 16 + qm;
#pragma unroll
      for (int r = 0; r < 4; r++) {
        int node = node0 + wv * 32 + mt * 16 + quad * 4 + r;
        if (node < N_NODES)
          support[(size_t)node * D_OUT + col] = acc[mt][nt][r] + bias[nt];
      }
    }
  }
}

// K1: FULL GEMM || FULL hist in one dispatch (overlap; GEMM blocks first)
__global__ __launch_bounds__(256, 2) void gemm_hist_kernel(
    const float* __restrict__ input, const short* __restrict__ wt_hi,
    const short* __restrict__ wt_lo, const float* __restrict__ b,
    float* __restrict__ support, const int* __restrict__ erow,
    int* __restrict__ counts, int* __restrict__ pos_e) {
  if (blockIdx.x < GEMM_BLOCKS) {
    gemm_body(blockIdx.x, input, wt_hi, wt_lo, b, support);
  } else {
    int e = (blockIdx.x - GEMM_BLOCKS) * 256 + threadIdx.x;
    if (e < N_EDGES) pos_e[e] = atomicAdd(&counts[erow[e]], 1);
  }
}

// K2: atomic-free CSR bucket scatter
__global__ __launch_bounds__(256) void build_kernel(
    const int* __restrict__ erow, const int* __restrict__ ecol,
    const float* __restrict__ eval, const int* __restrict__ offsets,
    const int* __restrict__ pos_e, int2* __restrict__ csr_ev) {
  int e = blockIdx.x * 256 + threadIdx.x;
  if (e < N_EDGES) {
    int idx = offsets[erow[e]] + pos_e[e];
    csr_ev[idx] = make_int2(ecol[e], __float_as_int(eval[e]));
  }
}

// ---------------------------------------------------------------------------
// 3-phase exclusive scan over counts (verified)
// ---------------------------------------------------------------------------
__global__ __launch_bounds__(256) void scan_phase1(const int* __restrict__ counts,
                                                   int* __restrict__ bsums) {
  __shared__ int ts[256];
  int t = threadIdx.x;
  int idx0 = blockIdx.x * SCAN_CHUNK + t * 4;
  int s = 0;
#pragma unroll
  for (int i = 0; i < 4; i++)
    if (idx0 + i < N_NODES) s += counts[idx0 + i];
  ts[t] = s;
  __syncthreads();
#pragma unroll
  for (int off = 128; off > 0; off >>= 1) {
    if (t < off) ts[t] += ts[t + off];
    __syncthreads();
  }
  if (t == 0) bsums[blockIdx.x] = ts[0];
}

__global__ __launch_bounds__(128) void scan_phase2(int* __restrict__ bsums) {
  __shared__ int s[128];
  int t = threadIdx.x;
  int v = (t < SCAN_BLOCKS) ? bsums[t] : 0;
  s[t] = v;
  __syncthreads();
#pragma unroll
  for (int off = 1; off < 128; off <<= 1) {
    int x = (t >= off) ? s[t - off] : 0;
    __syncthreads();
    s[t] += x;
    __syncthreads();
  }
  if (t < SCAN_BLOCKS) bsums[t] = s[t] - v;  // exclusive
}

__global__ __launch_bounds__(256) void scan_phase3(int* __restrict__ counts,
                                                   const int* __restrict__ bsums) {
  __shared__ int ts[256];
  int t = threadIdx.x;
  int b = blockIdx.x;
  int idx0 = b * SCAN_CHUNK + t * 4;
  int v[4];
  int s = 0;
#pragma unroll
  for (int i = 0; i < 4; i++) {
    v[i] = (idx0 + i < N_NODES) ? counts[idx0 + i] : 0;
    s += v[i];
  }
  ts[t] = s;
  __syncthreads();
#pragma unroll
  for (int off = 1; off < 256; off <<= 1) {
    int x = (t >= off) ? ts[t - off] : 0;
    __syncthreads();
    ts[t] += x;
    __syncthreads();
  }
  int run = bsums[b] + ts[t] - s;
#pragma unroll
  for (int i = 0; i < 4; i++) {
    int idx = idx0 + i;
    if (idx < N_NODES) counts[idx] = run;
    run += v[i];
  }
  if (b == 0 && t == 0) counts[N_NODES] = N_EDGES;
}

// ---------------------------------------------------------------------------
// Gather-aggregate + fused tanh.  32 lanes x float4 per row.
// Always-8-wide predicated batches (clamped index, zeroed val for overhang
// -> bit-identical result, no serial tail) + software-pipelined edge
// prefetch (batch j+1's csr_ev loads issued before batch j's FMAs):
// exactly ONE serialized gather latency per 8 edges.
// ---------------------------------------------------------------------------
__global__ __launch_bounds__(256) void agg_kernel(
    const int* __restrict__ offsets, const int2* __restrict__ csr_ev,
    const float* __restrict__ support, float* __restrict__ out) {
  int r = blockIdx.x * 8 + (threadIdx.x >> 5);
  int l4 = (threadIdx.x & 31) * 4;          // feature quad
  int beg = offsets[r];
  int end = offsets[r + 1];
  float4 acc = make_float4(0.f, 0.f, 0.f, 0.f);

  if (end > beg) {
    int2 e[8], en[8];
#pragma unroll
    for (int u = 0; u < 8; u++) {           // prologue batch (predicated)
      int idx = beg + u;
      int c = idx < end ? idx : end - 1;
      e[u] = csr_ev[c];
      if (idx >= end) e[u].y = 0;           // val := 0.0f
    }
    for (int j = beg; j < end; j += 8) {
      int jn = j + 8;
      if (jn < end) {                       // prefetch next batch
#pragma unroll
        for (int u = 0; u < 8; u++) {
          int idx = jn + u;
          int c = idx < end ? idx : end - 1;
          en[u] = csr_ev[c];
          if (idx >= end) en[u].y = 0;
        }
      }
      float4 s[8];
#pragma unroll
      for (int u = 0; u < 8; u++)
        s[u] = *(const float4*)(support + (size_t)e[u].x * D_OUT + l4);
#pragma unroll
      for (int u = 0; u < 8; u++) {
        float v = __int_as_float(e[u].y);
        acc.x = fmaf(v, s[u].x, acc.x);
        acc.y = fmaf(v, s[u].y, acc.y);
        acc.z = fmaf(v, s[u].z, acc.z);
        acc.w = fmaf(v, s[u].w, acc.w);
      }
#pragma unroll
      for (int u = 0; u < 8; u++) e[u] = en[u];
    }
  }
  *(float4*)(out + (size_t)r * D_OUT + l4) =
      make_float4(tanhf(acc.x), tanhf(acc.y), tanhf(acc.z), tanhf(acc.w));
}

extern "C" void kernel_launch(void* const* d_in, const int* in_sizes, int n_in,
                              void* d_out, int out_size, void* d_ws, size_t ws_size,
                              hipStream_t stream) {
  const float* input = (const float*)d_in[0];
  const int* erow = (const int*)d_in[1];
  const int* ecol = (const int*)d_in[2];
  const float* eval = (const float*)d_in[3];
  const float* W = (const float*)d_in[4];
  const float* b = (const float*)d_in[5];
  float* out = (float*)d_out;

  char* ws = (char*)d_ws;
  float* support = (float*)(ws + OFF_SUPPORT);
  int* counts = (int*)(ws + OFF_COUNTS);  // becomes offsets after scan
  int2* csr_ev = (int2*)(ws + OFF_CSREV);
  int* bsums = (int*)(ws + OFF_BSUMS);
  short* wt_hi = (short*)(ws + OFF_WTHI);
  short* wt_lo = (short*)(ws + OFF_WTLO);
  int* pos_e = (int*)d_out;  // d_out as scratch; agg overwrites it last

  // K0: convert W once (transposed bf16 hi/lo) + zero counts
  hipLaunchKernelGGL(wconv_kernel, dim3((D_IN * D_OUT) / 256), dim3(256), 0,
                     stream, W, wt_hi, wt_lo, counts);

  // K1: full MFMA-GEMM || full histogram (one dispatch, overlapped)
  hipLaunchKernelGGL(gemm_hist_kernel, dim3(GEMM_BLOCKS + EDGE_BLOCKS),
                     dim3(256), 0, stream, input, wt_hi, wt_lo, b, support,
                     erow, counts, pos_e);
  // exclusive scan: counts -> offsets
  hipLaunchKernelGGL(scan_phase1, dim3(SCAN_BLOCKS), dim3(256), 0, stream,
                     counts, bsums);
  hipLaunchKernelGGL(scan_phase2, dim3(1), dim3(128), 0, stream, bsums);
  hipLaunchKernelGGL(scan_phase3, dim3(SCAN_BLOCKS), dim3(256), 0, stream,
                     counts, bsums);
  // K2: atomic-free CSR bucket scatter
  hipLaunchKernelGGL(build_kernel, dim3(EDGE_BLOCKS), dim3(256), 0, stream,
                     erow, ecol, eval, counts, pos_e, csr_ev);
  // out = tanh(A_csr * support)
  hipLaunchKernelGGL(agg_kernel, dim3(N_NODES / 8), dim3(256), 0, stream,
                     counts, csr_ev, support, out);
}